// Round 1
// baseline (1281.352 us; speedup 1.0000x reference)
//
#include <hip/hip_runtime.h>
#include <stdint.h>

// ---------- constants ----------
static constexpr int SEQ = 1024;   // sen_len == sp_len == p_len
static constexpr int NH  = 12;
static constexpr int DH  = 64;
static constexpr int EMB = 768;
static constexpr int NB  = 8;

typedef __attribute__((ext_vector_type(8))) short bf16x8;
typedef __attribute__((ext_vector_type(4))) short s16x4;
typedef __attribute__((ext_vector_type(4))) float f32x4;

__device__ __forceinline__ float b2f(short s) {
    return __uint_as_float(((unsigned)(unsigned short)s) << 16);
}
__device__ __forceinline__ unsigned short f2b(float f) {
    unsigned u = __float_as_uint(f);
    unsigned rnd = 0x7fffu + ((u >> 16) & 1u);
    return (unsigned short)((u + rnd) >> 16);
}

__device__ __forceinline__ void gload_lds16(const void* g, void* l) {
    auto gp = reinterpret_cast<const __attribute__((address_space(1))) unsigned*>(
        reinterpret_cast<uintptr_t>(g));
    auto lp = reinterpret_cast<__attribute__((address_space(3))) unsigned*>(
        reinterpret_cast<uintptr_t>(l));
    __builtin_amdgcn_global_load_lds(gp, lp, 16, 0, 0);
}

// ---------- fp32 -> bf16 convert ----------
__global__ __launch_bounds__(256) void cvt_bf16(const float* __restrict__ in,
                                                unsigned short* __restrict__ out, int n4) {
    int i = blockIdx.x * 256 + threadIdx.x;
    if (i >= n4) return;
    float4 v = ((const float4*)in)[i];
    s16x4 o;
    o[0] = (short)f2b(v.x); o[1] = (short)f2b(v.y);
    o[2] = (short)f2b(v.z); o[3] = (short)f2b(v.w);
    ((s16x4*)out)[i] = o;
}

// ---------- transpose v [z][1024][64] -> vT [z][64][1024] ----------
__global__ __launch_bounds__(256) void transpose_v(const unsigned short* __restrict__ v,
                                                   unsigned short* __restrict__ vt) {
    const int zz = blockIdx.y;          // head-batch 0..95
    const int s0 = blockIdx.x * 64;     // 16 blocks of 64 s
    __shared__ unsigned short tile[64][80];
    const int t = threadIdx.x;
    {
        int rs = t >> 2;                // s within tile
        int cd = (t & 3) * 16;          // d start
        const unsigned short* src = v + ((size_t)zz * SEQ + s0 + rs) * DH + cd;
        *(bf16x8*)&tile[rs][cd]     = *(const bf16x8*)src;
        *(bf16x8*)&tile[rs][cd + 8] = *(const bf16x8*)(src + 8);
    }
    __syncthreads();
    {
        int rd = t >> 2;                // d row
        int cs = (t & 3) * 16;          // s chunk
        unsigned short o[16];
        #pragma unroll
        for (int j = 0; j < 16; j++) o[j] = tile[cs + j][rd];
        unsigned short* dst = vt + ((size_t)zz * DH + rd) * SEQ + s0 + cs;
        *(bf16x8*)dst       = *(const bf16x8*)&o[0];
        *(bf16x8*)(dst + 8) = *(const bf16x8*)&o[8];
    }
}

// ---------- row softmax over contiguous 1024 (in place, bf16) ----------
__global__ __launch_bounds__(256) void softmax_rows(unsigned short* __restrict__ x) {
    unsigned short* p = x + (size_t)blockIdx.x * 1024;
    const int t = threadIdx.x, wave = t >> 6, lane = t & 63;
    __shared__ float red[4];
    s16x4 raw = *(const s16x4*)(p + t * 4);
    float f0 = b2f(raw[0]), f1 = b2f(raw[1]), f2 = b2f(raw[2]), f3 = b2f(raw[3]);
    float m = fmaxf(fmaxf(f0, f1), fmaxf(f2, f3));
    #pragma unroll
    for (int o = 32; o > 0; o >>= 1) m = fmaxf(m, __shfl_down(m, o));
    if (lane == 0) red[wave] = m;
    __syncthreads();
    float mx = fmaxf(fmaxf(red[0], red[1]), fmaxf(red[2], red[3]));
    __syncthreads();
    float e0 = __expf(f0 - mx), e1 = __expf(f1 - mx), e2 = __expf(f2 - mx), e3 = __expf(f3 - mx);
    float s = e0 + e1 + e2 + e3;
    #pragma unroll
    for (int o = 32; o > 0; o >>= 1) s += __shfl_down(s, o);
    if (lane == 0) red[wave] = s;
    __syncthreads();
    float inv = 1.0f / (red[0] + red[1] + red[2] + red[3]);
    s16x4 o;
    o[0] = (short)f2b(e0 * inv); o[1] = (short)f2b(e1 * inv);
    o[2] = (short)f2b(e2 * inv); o[3] = (short)f2b(e3 * inv);
    *(s16x4*)(p + t * 4) = o;
}

// ---------- templated NT GEMM: C[M,N] = alpha * (A[M,K] @ B[N,K]^T) (+bias) ----------
// MODE 0: bf16 row-major out (ldc), *alpha
// MODE 1: projection: (acc + bias[col]) * alpha -> bf16 head-split [b,h,s,d], row=b*1024+s, col=h*64+d
// MODE 2: fp32 row-major out + bias[col] (final output)
// MODE 3: pv: bf16 head-merge out [b, p, h*64+d]; z maps to (b,h) via head0
template<int WGM, int WGN, int WM, int WN, int MODE>
__global__ __launch_bounds__(256) void gemm_nt(
    const unsigned short* __restrict__ A, const unsigned short* __restrict__ B,
    void* __restrict__ Cout, const float* __restrict__ bias, float alpha,
    int Kc, int lda, int ldb, int ldc,
    size_t strideA, size_t strideB, size_t strideC, int head0)
{
    constexpr int BM = WGM * WM * 16, BN = WGN * WN * 16, BK = 64;
    const int z = blockIdx.z;
    A += (size_t)z * strideA;
    B += (size_t)z * strideB;
    const int m0 = blockIdx.x * BM, n0 = blockIdx.y * BN;
    __shared__ unsigned short lA[BM * BK];
    __shared__ unsigned short lB[BN * BK];
    const int tid = threadIdx.x, wave = tid >> 6, lane = tid & 63;
    const int wm = wave % WGM, wn = wave / WGM;
    const int fr = lane & 15, fq = lane >> 4;
    const int lrow = lane >> 3, lcol = (lane & 7) * 8;
    f32x4 acc[WM][WN] = {};

    for (int k0 = 0; k0 < Kc; k0 += BK) {
        __syncthreads();
        #pragma unroll
        for (int cc = 0; cc < BM / 32; cc++) {
            int c = cc * 4 + wave;
            const unsigned short* src = A + (size_t)(m0 + c * 8 + lrow) * lda + k0 + lcol;
            gload_lds16(src, &lA[c * 512]);
        }
        #pragma unroll
        for (int cc = 0; cc < BN / 32; cc++) {
            int c = cc * 4 + wave;
            const unsigned short* src = B + (size_t)(n0 + c * 8 + lrow) * ldb + k0 + lcol;
            gload_lds16(src, &lB[c * 512]);
        }
        __syncthreads();
        #pragma unroll
        for (int kk = 0; kk < BK; kk += 32) {
            bf16x8 aF[WM], bF[WN];
            #pragma unroll
            for (int i = 0; i < WM; i++)
                aF[i] = *(const bf16x8*)&lA[(wm * WM * 16 + i * 16 + fr) * BK + kk + fq * 8];
            #pragma unroll
            for (int j = 0; j < WN; j++)
                bF[j] = *(const bf16x8*)&lB[(wn * WN * 16 + j * 16 + fr) * BK + kk + fq * 8];
            #pragma unroll
            for (int i = 0; i < WM; i++)
                #pragma unroll
                for (int j = 0; j < WN; j++)
                    acc[i][j] = __builtin_amdgcn_mfma_f32_16x16x32_bf16(aF[i], bF[j], acc[i][j], 0, 0, 0);
        }
    }

    #pragma unroll
    for (int i = 0; i < WM; i++) {
        const int row0 = m0 + wm * WM * 16 + i * 16 + fq * 4;
        #pragma unroll
        for (int j = 0; j < WN; j++) {
            const int col = n0 + wn * WN * 16 + j * 16 + fr;
            #pragma unroll
            for (int r = 0; r < 4; r++) {
                const int row = row0 + r;
                float val = acc[i][j][r];
                if constexpr (MODE == 0) {
                    unsigned short* C = (unsigned short*)Cout + (size_t)z * strideC;
                    C[(size_t)row * ldc + col] = f2b(val * alpha);
                } else if constexpr (MODE == 1) {
                    unsigned short* C = (unsigned short*)Cout;
                    float v = (val + bias[col]) * alpha;
                    int b = row >> 10, s = row & 1023;
                    int h = col >> 6,  d = col & 63;
                    C[(((size_t)b * NH + h) * SEQ + s) * DH + d] = f2b(v);
                } else if constexpr (MODE == 2) {
                    float* C = (float*)Cout;
                    C[(size_t)row * ldc + col] = val + bias[col];
                } else {
                    unsigned short* C = (unsigned short*)Cout;
                    int zz = head0 + z;
                    int b = zz / NH, h = zz - b * NH;
                    C[((size_t)b * SEQ + row) * EMB + h * DH + col] = f2b(val);
                }
            }
        }
    }
}

// ---------- launcher ----------
extern "C" void kernel_launch(void* const* d_in, const int* in_sizes, int n_in,
                              void* d_out, int out_size, void* d_ws, size_t ws_size,
                              hipStream_t stream) {
    (void)in_sizes; (void)n_in; (void)out_size;
    const float* l    = (const float*)d_in[0];
    const float* sp   = (const float*)d_in[1];
    const float* p    = (const float*)d_in[2];
    const float* Wq   = (const float*)d_in[3];
    const float* bq   = (const float*)d_in[4];
    const float* Wksp = (const float*)d_in[5];
    const float* bksp = (const float*)d_in[6];
    const float* Wkp  = (const float*)d_in[7];
    const float* bkp  = (const float*)d_in[8];
    const float* Wvsp = (const float*)d_in[9];
    const float* bvsp = (const float*)d_in[10];
    const float* Wo   = (const float*)d_in[13];
    const float* bo   = (const float*)d_in[14];

    const size_t TOK  = (size_t)NB * SEQ * EMB;      // 6291456 elems
    const size_t WSZ  = (size_t)EMB * EMB;           // 589824 elems
    const size_t HB   = (size_t)SEQ * DH;            // 65536 elems per (b,h)
    const size_t MAT  = (size_t)SEQ * SEQ;           // 1048576 elems per (b,h)

    char* wp = (char*)d_ws;
    auto alloc = [&](size_t bytes) {
        char* r = wp;
        wp += (bytes + 255) & ~(size_t)255;
        return r;
    };
    unsigned short* l_bf    = (unsigned short*)alloc(TOK * 2);
    unsigned short* sp_bf   = (unsigned short*)alloc(TOK * 2);
    unsigned short* p_bf    = (unsigned short*)alloc(TOK * 2);
    unsigned short* Wq_bf   = (unsigned short*)alloc(WSZ * 2);
    unsigned short* Wksp_bf = (unsigned short*)alloc(WSZ * 2);
    unsigned short* Wkp_bf  = (unsigned short*)alloc(WSZ * 2);
    unsigned short* Wvsp_bf = (unsigned short*)alloc(WSZ * 2);
    unsigned short* Wo_bf   = (unsigned short*)alloc(WSZ * 2);
    unsigned short* qb      = (unsigned short*)alloc(TOK * 2);  // [b,h,s,d]
    unsigned short* kspb    = (unsigned short*)alloc(TOK * 2);  // [b,h,k,d]
    unsigned short* kpb     = (unsigned short*)alloc(TOK * 2);  // [b,h,p,d]
    unsigned short* vb      = (unsigned short*)alloc(TOK * 2);  // [b,h,k,d]
    unsigned short* vTb     = (unsigned short*)alloc(TOK * 2);  // [b,h,d,k]
    unsigned short* attn    = (unsigned short*)alloc(TOK * 2);  // [b,p,e]

    size_t used = (size_t)(wp - (char*)d_ws);
    size_t remain = (ws_size > used) ? (ws_size - used) : 0;
    const size_t perBatch = 3 * (size_t)NH * MAT * 2;           // At+Bt+C per batch
    int chunk = 8;
    while (chunk > 1 && (size_t)chunk * perBatch > remain) chunk >>= 1;
    unsigned short* At = (unsigned short*)alloc((size_t)chunk * NH * MAT * 2); // [z][k][s]
    unsigned short* Bt = (unsigned short*)alloc((size_t)chunk * NH * MAT * 2); // [z][p][s]
    unsigned short* Cm = (unsigned short*)alloc((size_t)chunk * NH * MAT * 2); // [z][p][k]

    const float scale = 0.125f;  // 64^-0.5

    // 1. convert inputs & weights to bf16
    cvt_bf16<<<dim3(TOK / 4 / 256), 256, 0, stream>>>(l,  l_bf,  (int)(TOK / 4));
    cvt_bf16<<<dim3(TOK / 4 / 256), 256, 0, stream>>>(sp, sp_bf, (int)(TOK / 4));
    cvt_bf16<<<dim3(TOK / 4 / 256), 256, 0, stream>>>(p,  p_bf,  (int)(TOK / 4));
    cvt_bf16<<<dim3(WSZ / 4 / 256), 256, 0, stream>>>(Wq,   Wq_bf,   (int)(WSZ / 4));
    cvt_bf16<<<dim3(WSZ / 4 / 256), 256, 0, stream>>>(Wksp, Wksp_bf, (int)(WSZ / 4));
    cvt_bf16<<<dim3(WSZ / 4 / 256), 256, 0, stream>>>(Wkp,  Wkp_bf,  (int)(WSZ / 4));
    cvt_bf16<<<dim3(WSZ / 4 / 256), 256, 0, stream>>>(Wvsp, Wvsp_bf, (int)(WSZ / 4));
    cvt_bf16<<<dim3(WSZ / 4 / 256), 256, 0, stream>>>(Wo,   Wo_bf,   (int)(WSZ / 4));

    // 2. projections -> head-split bf16, scaled
    const dim3 gproj(64, 6, 1);
    gemm_nt<2,2,4,4,1><<<gproj, 256, 0, stream>>>(l_bf,  Wq_bf,   qb,   bq,   scale, EMB, EMB, EMB, 0, 0, 0, 0, 0);
    gemm_nt<2,2,4,4,1><<<gproj, 256, 0, stream>>>(sp_bf, Wksp_bf, kspb, bksp, scale, EMB, EMB, EMB, 0, 0, 0, 0, 0);
    gemm_nt<2,2,4,4,1><<<gproj, 256, 0, stream>>>(p_bf,  Wkp_bf,  kpb,  bkp,  scale, EMB, EMB, EMB, 0, 0, 0, 0, 0);
    gemm_nt<2,2,4,4,1><<<gproj, 256, 0, stream>>>(sp_bf, Wvsp_bf, vb,   bvsp, scale, EMB, EMB, EMB, 0, 0, 0, 0, 0);

    // 3. v transpose [z][k][d] -> [z][d][k]
    transpose_v<<<dim3(16, NB * NH), 256, 0, stream>>>(vb, vTb);

    // 4. attention, chunked over batches
    for (int b0 = 0; b0 < NB; b0 += chunk) {
        const int ZH = chunk * NH;
        const int head0 = b0 * NH;
        const unsigned short* qz   = qb   + (size_t)head0 * HB;
        const unsigned short* kspz = kspb + (size_t)head0 * HB;
        const unsigned short* kpz  = kpb  + (size_t)head0 * HB;
        const unsigned short* vTz  = vTb  + (size_t)head0 * HB;
        // logits (transposed): At[k,s] = ksp[k]·q[s];  Bt[p,s] = kp[p]·q[s]
        gemm_nt<2,2,4,4,0><<<dim3(8, 8, ZH), 256, 0, stream>>>(kspz, qz, At, nullptr, 1.0f,
            DH, DH, DH, SEQ, HB, HB, MAT, 0);
        gemm_nt<2,2,4,4,0><<<dim3(8, 8, ZH), 256, 0, stream>>>(kpz,  qz, Bt, nullptr, 1.0f,
            DH, DH, DH, SEQ, HB, HB, MAT, 0);
        // softmax over s (contiguous rows)
        softmax_rows<<<dim3(ZH * SEQ), 256, 0, stream>>>(At);
        softmax_rows<<<dim3(ZH * SEQ), 256, 0, stream>>>(Bt);
        // sp2p: C[p,k] = sum_s Bt[p,s] * At[k,s]
        gemm_nt<2,2,4,4,0><<<dim3(8, 8, ZH), 256, 0, stream>>>(Bt, At, Cm, nullptr, 1.0f,
            SEQ, SEQ, SEQ, SEQ, MAT, MAT, MAT, 0);
        // softmax over k (contiguous rows)
        softmax_rows<<<dim3(ZH * SEQ), 256, 0, stream>>>(Cm);
        // pv: attn[b, p, h*64+d] = sum_k C[p,k] * vT[d,k]
        gemm_nt<4,1,2,4,3><<<dim3(8, 1, ZH), 256, 0, stream>>>(Cm, vTz, attn, nullptr, 1.0f,
            SEQ, SEQ, SEQ, 0, MAT, HB, 0, head0);
    }

    // 5. output projection -> fp32 d_out
    gemm_nt<2,2,4,4,2><<<gproj, 256, 0, stream>>>(attn, Wo_bf, d_out, bo, 1.0f,
        EMB, EMB, EMB, EMB, 0, 0, 0, 0);
}

// Round 2
// 1058.353 us; speedup vs baseline: 1.2107x; 1.2107x over previous
//
#include <hip/hip_runtime.h>
#include <stdint.h>

// ---------- constants ----------
static constexpr int SEQ = 1024;   // sen_len == sp_len == p_len
static constexpr int NH  = 12;
static constexpr int DH  = 64;
static constexpr int EMB = 768;
static constexpr int NB  = 8;

typedef __attribute__((ext_vector_type(8))) short bf16x8;
typedef __attribute__((ext_vector_type(4))) short s16x4;
typedef __attribute__((ext_vector_type(4))) float f32x4;

__device__ __forceinline__ float b2f(short s) {
    return __uint_as_float(((unsigned)(unsigned short)s) << 16);
}
__device__ __forceinline__ unsigned short f2b(float f) {
    unsigned u = __float_as_uint(f);
    unsigned rnd = 0x7fffu + ((u >> 16) & 1u);
    return (unsigned short)((u + rnd) >> 16);
}

__device__ __forceinline__ void gload_lds16(const void* g, void* l) {
    auto gp = reinterpret_cast<const __attribute__((address_space(1))) unsigned*>(
        reinterpret_cast<uintptr_t>(g));
    auto lp = reinterpret_cast<__attribute__((address_space(3))) unsigned*>(
        reinterpret_cast<uintptr_t>(l));
    __builtin_amdgcn_global_load_lds(gp, lp, 16, 0, 0);
}

// ---------- fp32 -> bf16 convert ----------
__global__ __launch_bounds__(256) void cvt_bf16(const float* __restrict__ in,
                                                unsigned short* __restrict__ out, int n4) {
    int i = blockIdx.x * 256 + threadIdx.x;
    if (i >= n4) return;
    float4 v = ((const float4*)in)[i];
    s16x4 o;
    o[0] = (short)f2b(v.x); o[1] = (short)f2b(v.y);
    o[2] = (short)f2b(v.z); o[3] = (short)f2b(v.w);
    ((s16x4*)out)[i] = o;
}

// ---------- transpose v [z][1024][64] -> vT [z][64][1024] ----------
__global__ __launch_bounds__(256) void transpose_v(const unsigned short* __restrict__ v,
                                                   unsigned short* __restrict__ vt) {
    const int zz = blockIdx.y;          // head-batch 0..95
    const int s0 = blockIdx.x * 64;     // 16 blocks of 64 s
    __shared__ unsigned short tile[64][80];
    const int t = threadIdx.x;
    {
        int rs = t >> 2;                // s within tile
        int cd = (t & 3) * 16;          // d start
        const unsigned short* src = v + ((size_t)zz * SEQ + s0 + rs) * DH + cd;
        *(bf16x8*)&tile[rs][cd]     = *(const bf16x8*)src;
        *(bf16x8*)&tile[rs][cd + 8] = *(const bf16x8*)(src + 8);
    }
    __syncthreads();
    {
        int rd = t >> 2;                // d row
        int cs = (t & 3) * 16;          // s chunk
        unsigned short o[16];
        #pragma unroll
        for (int j = 0; j < 16; j++) o[j] = tile[cs + j][rd];
        unsigned short* dst = vt + ((size_t)zz * DH + rd) * SEQ + s0 + cs;
        *(bf16x8*)dst       = *(const bf16x8*)&o[0];
        *(bf16x8*)(dst + 8) = *(const bf16x8*)&o[8];
    }
}

// ---------- row softmax: one wave per 1024-row, 4 rows/block, in place bf16 ----------
__global__ __launch_bounds__(256) void softmax_rows(unsigned short* __restrict__ x) {
    const int row  = blockIdx.x * 4 + (threadIdx.x >> 6);
    const int lane = threadIdx.x & 63;
    unsigned short* p = x + (size_t)row * 1024 + lane * 16;
    bf16x8 r0 = *(const bf16x8*)p;
    bf16x8 r1 = *(const bf16x8*)(p + 8);
    float f[16];
    #pragma unroll
    for (int j = 0; j < 8; j++) { f[j] = b2f(r0[j]); f[8 + j] = b2f(r1[j]); }
    float m = f[0];
    #pragma unroll
    for (int j = 1; j < 16; j++) m = fmaxf(m, f[j]);
    #pragma unroll
    for (int o = 1; o < 64; o <<= 1) m = fmaxf(m, __shfl_xor(m, o));
    float s = 0.0f;
    #pragma unroll
    for (int j = 0; j < 16; j++) { f[j] = __expf(f[j] - m); s += f[j]; }
    #pragma unroll
    for (int o = 1; o < 64; o <<= 1) s += __shfl_xor(s, o);
    float inv = 1.0f / s;
    bf16x8 o0, o1;
    #pragma unroll
    for (int j = 0; j < 8; j++) {
        o0[j] = (short)f2b(f[j] * inv);
        o1[j] = (short)f2b(f[8 + j] * inv);
    }
    *(bf16x8*)p = o0;
    *(bf16x8*)(p + 8) = o1;
}

// ---------- templated NT GEMM: C[M,N] = alpha * (A[M,K] @ B[N,K]^T) (+bias) ----------
// LDS layout is XOR-swizzled: slot (row r, 16B-chunk j) holds global chunk j^(r&7).
// global_load_lds forces dest = base + lane*16, so the swizzle is applied on the
// GLOBAL side at staging (lane loads chunk (lane&7)^(lane>>3)) and on the LDS
// side at fragment read (chunk ((kk>>3)+fq)^(fr&7)). Kills the 16-way bank
// conflict of the naive 128B-row-stride layout (was 26% of sp2p cycles).
// MODE 0: bf16 row-major out (ldc), *alpha
// MODE 1: projection: (acc + bias[col]) * alpha -> bf16 head-split [b,h,s,d]
// MODE 2: fp32 row-major out + bias[col] (final output)
// MODE 3: pv: bf16 head-merge out [b, p, h*64+d]; z maps to (b,h) via head0
template<int WGM, int WGN, int WM, int WN, int MODE>
__global__ __launch_bounds__(256) void gemm_nt(
    const unsigned short* __restrict__ A, const unsigned short* __restrict__ B,
    void* __restrict__ Cout, const float* __restrict__ bias, float alpha,
    int Kc, int lda, int ldb, int ldc,
    size_t strideA, size_t strideB, size_t strideC, int head0)
{
    constexpr int BM = WGM * WM * 16, BN = WGN * WN * 16, BK = 64;
    const int z = blockIdx.z;
    A += (size_t)z * strideA;
    B += (size_t)z * strideB;
    const int m0 = blockIdx.x * BM, n0 = blockIdx.y * BN;
    __shared__ unsigned short lA[BM * BK];
    __shared__ unsigned short lB[BN * BK];
    const int tid = threadIdx.x, wave = tid >> 6, lane = tid & 63;
    const int wm = wave % WGM, wn = wave / WGM;
    const int fr = lane & 15, fq = lane >> 4;
    const int frx = fr & 7;
    const int lrow = lane >> 3;
    const int lcol = ((lane & 7) ^ lrow) * 8;   // XOR-swizzled global chunk
    f32x4 acc[WM][WN] = {};

    for (int k0 = 0; k0 < Kc; k0 += BK) {
        __syncthreads();
        #pragma unroll
        for (int cc = 0; cc < BM / 32; cc++) {
            int c = cc * 4 + wave;
            const unsigned short* src = A + (size_t)(m0 + c * 8 + lrow) * lda + k0 + lcol;
            gload_lds16(src, &lA[c * 512]);
        }
        #pragma unroll
        for (int cc = 0; cc < BN / 32; cc++) {
            int c = cc * 4 + wave;
            const unsigned short* src = B + (size_t)(n0 + c * 8 + lrow) * ldb + k0 + lcol;
            gload_lds16(src, &lB[c * 512]);
        }
        __syncthreads();
        #pragma unroll
        for (int kk = 0; kk < BK; kk += 32) {
            bf16x8 aF[WM], bF[WN];
            #pragma unroll
            for (int i = 0; i < WM; i++)
                aF[i] = *(const bf16x8*)&lA[(wm * WM * 16 + i * 16 + fr) * BK +
                                            ((((kk >> 3) + fq) ^ frx) << 3)];
            #pragma unroll
            for (int j = 0; j < WN; j++)
                bF[j] = *(const bf16x8*)&lB[(wn * WN * 16 + j * 16 + fr) * BK +
                                            ((((kk >> 3) + fq) ^ frx) << 3)];
            #pragma unroll
            for (int i = 0; i < WM; i++)
                #pragma unroll
                for (int j = 0; j < WN; j++)
                    acc[i][j] = __builtin_amdgcn_mfma_f32_16x16x32_bf16(aF[i], bF[j], acc[i][j], 0, 0, 0);
        }
    }

    #pragma unroll
    for (int i = 0; i < WM; i++) {
        const int row0 = m0 + wm * WM * 16 + i * 16 + fq * 4;
        #pragma unroll
        for (int j = 0; j < WN; j++) {
            const int col = n0 + wn * WN * 16 + j * 16 + fr;
            #pragma unroll
            for (int r = 0; r < 4; r++) {
                const int row = row0 + r;
                float val = acc[i][j][r];
                if constexpr (MODE == 0) {
                    unsigned short* C = (unsigned short*)Cout + (size_t)z * strideC;
                    C[(size_t)row * ldc + col] = f2b(val * alpha);
                } else if constexpr (MODE == 1) {
                    unsigned short* C = (unsigned short*)Cout;
                    float v = (val + bias[col]) * alpha;
                    int b = row >> 10, s = row & 1023;
                    int h = col >> 6,  d = col & 63;
                    C[(((size_t)b * NH + h) * SEQ + s) * DH + d] = f2b(v);
                } else if constexpr (MODE == 2) {
                    float* C = (float*)Cout;
                    C[(size_t)row * ldc + col] = val + bias[col];
                } else {
                    unsigned short* C = (unsigned short*)Cout;
                    int zz = head0 + z;
                    int b = zz / NH, h = zz - b * NH;
                    C[((size_t)b * SEQ + row) * EMB + h * DH + col] = f2b(val);
                }
            }
        }
    }
}

// ---------- launcher ----------
extern "C" void kernel_launch(void* const* d_in, const int* in_sizes, int n_in,
                              void* d_out, int out_size, void* d_ws, size_t ws_size,
                              hipStream_t stream) {
    (void)in_sizes; (void)n_in; (void)out_size;
    const float* l    = (const float*)d_in[0];
    const float* sp   = (const float*)d_in[1];
    const float* p    = (const float*)d_in[2];
    const float* Wq   = (const float*)d_in[3];
    const float* bq   = (const float*)d_in[4];
    const float* Wksp = (const float*)d_in[5];
    const float* bksp = (const float*)d_in[6];
    const float* Wkp  = (const float*)d_in[7];
    const float* bkp  = (const float*)d_in[8];
    const float* Wvsp = (const float*)d_in[9];
    const float* bvsp = (const float*)d_in[10];
    const float* Wo   = (const float*)d_in[13];
    const float* bo   = (const float*)d_in[14];

    const size_t TOK  = (size_t)NB * SEQ * EMB;      // 6291456 elems
    const size_t WSZ  = (size_t)EMB * EMB;           // 589824 elems
    const size_t HB   = (size_t)SEQ * DH;            // 65536 elems per (b,h)
    const size_t MAT  = (size_t)SEQ * SEQ;           // 1048576 elems per (b,h)

    char* wp = (char*)d_ws;
    auto alloc = [&](size_t bytes) {
        char* r = wp;
        wp += (bytes + 255) & ~(size_t)255;
        return r;
    };
    unsigned short* l_bf    = (unsigned short*)alloc(TOK * 2);
    unsigned short* sp_bf   = (unsigned short*)alloc(TOK * 2);
    unsigned short* p_bf    = (unsigned short*)alloc(TOK * 2);
    unsigned short* Wq_bf   = (unsigned short*)alloc(WSZ * 2);
    unsigned short* Wksp_bf = (unsigned short*)alloc(WSZ * 2);
    unsigned short* Wkp_bf  = (unsigned short*)alloc(WSZ * 2);
    unsigned short* Wvsp_bf = (unsigned short*)alloc(WSZ * 2);
    unsigned short* Wo_bf   = (unsigned short*)alloc(WSZ * 2);
    unsigned short* qb      = (unsigned short*)alloc(TOK * 2);  // [b,h,s,d]
    unsigned short* kspb    = (unsigned short*)alloc(TOK * 2);  // [b,h,k,d]
    unsigned short* kpb     = (unsigned short*)alloc(TOK * 2);  // [b,h,p,d]
    unsigned short* vb      = (unsigned short*)alloc(TOK * 2);  // [b,h,k,d]
    unsigned short* vTb     = (unsigned short*)alloc(TOK * 2);  // [b,h,d,k]
    unsigned short* attn    = (unsigned short*)alloc(TOK * 2);  // [b,p,e]

    size_t used = (size_t)(wp - (char*)d_ws);
    size_t remain = (ws_size > used) ? (ws_size - used) : 0;
    const size_t perBatch = 3 * (size_t)NH * MAT * 2;           // At+Bt+C per batch
    int chunk = 8;
    while (chunk > 1 && (size_t)chunk * perBatch > remain) chunk >>= 1;
    unsigned short* At = (unsigned short*)alloc((size_t)chunk * NH * MAT * 2); // [z][k][s]
    unsigned short* Bt = (unsigned short*)alloc((size_t)chunk * NH * MAT * 2); // [z][p][s]
    unsigned short* Cm = (unsigned short*)alloc((size_t)chunk * NH * MAT * 2); // [z][p][k]

    const float scale = 0.125f;  // 64^-0.5

    // 1. convert inputs & weights to bf16
    cvt_bf16<<<dim3(TOK / 4 / 256), 256, 0, stream>>>(l,  l_bf,  (int)(TOK / 4));
    cvt_bf16<<<dim3(TOK / 4 / 256), 256, 0, stream>>>(sp, sp_bf, (int)(TOK / 4));
    cvt_bf16<<<dim3(TOK / 4 / 256), 256, 0, stream>>>(p,  p_bf,  (int)(TOK / 4));
    cvt_bf16<<<dim3(WSZ / 4 / 256), 256, 0, stream>>>(Wq,   Wq_bf,   (int)(WSZ / 4));
    cvt_bf16<<<dim3(WSZ / 4 / 256), 256, 0, stream>>>(Wksp, Wksp_bf, (int)(WSZ / 4));
    cvt_bf16<<<dim3(WSZ / 4 / 256), 256, 0, stream>>>(Wkp,  Wkp_bf,  (int)(WSZ / 4));
    cvt_bf16<<<dim3(WSZ / 4 / 256), 256, 0, stream>>>(Wvsp, Wvsp_bf, (int)(WSZ / 4));
    cvt_bf16<<<dim3(WSZ / 4 / 256), 256, 0, stream>>>(Wo,   Wo_bf,   (int)(WSZ / 4));

    // 2. projections -> head-split bf16, scaled
    const dim3 gproj(64, 6, 1);
    gemm_nt<2,2,4,4,1><<<gproj, 256, 0, stream>>>(l_bf,  Wq_bf,   qb,   bq,   scale, EMB, EMB, EMB, 0, 0, 0, 0, 0);
    gemm_nt<2,2,4,4,1><<<gproj, 256, 0, stream>>>(sp_bf, Wksp_bf, kspb, bksp, scale, EMB, EMB, EMB, 0, 0, 0, 0, 0);
    gemm_nt<2,2,4,4,1><<<gproj, 256, 0, stream>>>(p_bf,  Wkp_bf,  kpb,  bkp,  scale, EMB, EMB, EMB, 0, 0, 0, 0, 0);
    gemm_nt<2,2,4,4,1><<<gproj, 256, 0, stream>>>(sp_bf, Wvsp_bf, vb,   bvsp, scale, EMB, EMB, EMB, 0, 0, 0, 0, 0);

    // 3. v transpose [z][k][d] -> [z][d][k]
    transpose_v<<<dim3(16, NB * NH), 256, 0, stream>>>(vb, vTb);

    // 4. attention, chunked over batches
    for (int b0 = 0; b0 < NB; b0 += chunk) {
        const int ZH = chunk * NH;
        const int head0 = b0 * NH;
        const unsigned short* qz   = qb   + (size_t)head0 * HB;
        const unsigned short* kspz = kspb + (size_t)head0 * HB;
        const unsigned short* kpz  = kpb  + (size_t)head0 * HB;
        const unsigned short* vTz  = vTb  + (size_t)head0 * HB;
        // logits (transposed): At[k,s] = ksp[k]·q[s];  Bt[p,s] = kp[p]·q[s]
        gemm_nt<2,2,4,4,0><<<dim3(8, 8, ZH), 256, 0, stream>>>(kspz, qz, At, nullptr, 1.0f,
            DH, DH, DH, SEQ, HB, HB, MAT, 0);
        gemm_nt<2,2,4,4,0><<<dim3(8, 8, ZH), 256, 0, stream>>>(kpz,  qz, Bt, nullptr, 1.0f,
            DH, DH, DH, SEQ, HB, HB, MAT, 0);
        // softmax over s: At and Bt are adjacent allocations -> one launch
        softmax_rows<<<dim3(2 * ZH * SEQ / 4), 256, 0, stream>>>(At);
        // sp2p: C[p,k] = sum_s Bt[p,s] * At[k,s]
        gemm_nt<2,2,4,4,0><<<dim3(8, 8, ZH), 256, 0, stream>>>(Bt, At, Cm, nullptr, 1.0f,
            SEQ, SEQ, SEQ, SEQ, MAT, MAT, MAT, 0);
        // softmax over k (contiguous rows)
        softmax_rows<<<dim3(ZH * SEQ / 4), 256, 0, stream>>>(Cm);
        // pv: attn[b, p, h*64+d] = sum_k C[p,k] * vT[d,k]
        gemm_nt<4,1,2,4,3><<<dim3(8, 1, ZH), 256, 0, stream>>>(Cm, vTz, attn, nullptr, 1.0f,
            SEQ, SEQ, SEQ, 0, MAT, HB, 0, head0);
    }

    // 5. output projection -> fp32 d_out
    gemm_nt<2,2,4,4,2><<<gproj, 256, 0, stream>>>(attn, Wo_bf, d_out, bo, 1.0f,
        EMB, EMB, EMB, EMB, 0, 0, 0, 0);
}

// Round 3
// 1019.348 us; speedup vs baseline: 1.2570x; 1.0383x over previous
//
#include <hip/hip_runtime.h>
#include <stdint.h>

// ---------- constants ----------
static constexpr int SEQ = 1024;   // sen_len == sp_len == p_len
static constexpr int NH  = 12;
static constexpr int DH  = 64;
static constexpr int EMB = 768;
static constexpr int NB  = 8;

typedef __attribute__((ext_vector_type(8))) short bf16x8;
typedef __attribute__((ext_vector_type(4))) short s16x4;
typedef __attribute__((ext_vector_type(4))) float f32x4;

__device__ __forceinline__ float b2f(short s) {
    return __uint_as_float(((unsigned)(unsigned short)s) << 16);
}
__device__ __forceinline__ unsigned short f2b(float f) {
    unsigned u = __float_as_uint(f);
    unsigned rnd = 0x7fffu + ((u >> 16) & 1u);
    return (unsigned short)((u + rnd) >> 16);
}

__device__ __forceinline__ void gload_lds16(const void* g, void* l) {
    auto gp = reinterpret_cast<const __attribute__((address_space(1))) unsigned*>(
        reinterpret_cast<uintptr_t>(g));
    auto lp = reinterpret_cast<__attribute__((address_space(3))) unsigned*>(
        reinterpret_cast<uintptr_t>(l));
    __builtin_amdgcn_global_load_lds(gp, lp, 16, 0, 0);
}

// ---------- fp32 -> bf16 convert ----------
__global__ __launch_bounds__(256) void cvt_bf16(const float* __restrict__ in,
                                                unsigned short* __restrict__ out, int n4) {
    int i = blockIdx.x * 256 + threadIdx.x;
    if (i >= n4) return;
    float4 v = ((const float4*)in)[i];
    s16x4 o;
    o[0] = (short)f2b(v.x); o[1] = (short)f2b(v.y);
    o[2] = (short)f2b(v.z); o[3] = (short)f2b(v.w);
    ((s16x4*)out)[i] = o;
}

// ---------- transpose v [z][1024][64] -> vT [z][64][1024] ----------
__global__ __launch_bounds__(256) void transpose_v(const unsigned short* __restrict__ v,
                                                   unsigned short* __restrict__ vt) {
    const int zz = blockIdx.y;          // head-batch 0..95
    const int s0 = blockIdx.x * 64;     // 16 blocks of 64 s
    __shared__ unsigned short tile[64][80];
    const int t = threadIdx.x;
    {
        int rs = t >> 2;                // s within tile
        int cd = (t & 3) * 16;          // d start
        const unsigned short* src = v + ((size_t)zz * SEQ + s0 + rs) * DH + cd;
        *(bf16x8*)&tile[rs][cd]     = *(const bf16x8*)src;
        *(bf16x8*)&tile[rs][cd + 8] = *(const bf16x8*)(src + 8);
    }
    __syncthreads();
    {
        int rd = t >> 2;                // d row
        int cs = (t & 3) * 16;          // s chunk
        unsigned short o[16];
        #pragma unroll
        for (int j = 0; j < 16; j++) o[j] = tile[cs + j][rd];
        unsigned short* dst = vt + ((size_t)zz * DH + rd) * SEQ + s0 + cs;
        *(bf16x8*)dst       = *(const bf16x8*)&o[0];
        *(bf16x8*)(dst + 8) = *(const bf16x8*)&o[8];
    }
}

// ---------- templated NT GEMM: C[M,N] = A[M,K] @ B[N,K]^T variants ----------
// LDS layout is XOR-swizzled: slot (row r, 16B-chunk j) holds global chunk j^(r&7)
// (global_load_lds pins LDS dest to base+lane*16, so the swizzle is applied on
// the global side at staging and on the LDS side at fragment read). Kills the
// 16-way bank conflict of the naive 128B-row-stride layout.
//
// MODE 1: projection: (acc + bias[col]) * alpha -> bf16 head-split [b,h,s,d]
// MODE 2: fp32 row-major out + bias[col] (final output)
// MODE 3: pv: (val * 1/srow[row]) -> bf16 head-merge out [b, p, h*64+d]
// MODE 4: logits: e=exp(val) -> bf16 out; atomicAdd row sums into rsum[row]
// MODE 5: sp2p: e=exp(val/(srow[row]*scol[col])) -> bf16; atomicAdd rsum[row]
// Softmax normalizers factor out of the s-contraction (both first softmaxes
// normalize along s), so MODE 4/5/3 together implement
// softmax_k( softmax_s(B)·softmax_s(A)^T ) · V with zero extra passes.
// exp without max-subtraction is safe: logits have |x| < ~0.3 by construction.
template<int WGM, int WGN, int WM, int WN, int MODE>
__global__ __launch_bounds__(256) void gemm_nt(
    const unsigned short* __restrict__ A, const unsigned short* __restrict__ B,
    void* __restrict__ Cout, const float* __restrict__ bias, float alpha,
    int Kc, int lda, int ldb, int ldc,
    size_t strideA, size_t strideB, size_t strideC, int head0,
    float* __restrict__ rsum, const float* __restrict__ srow,
    const float* __restrict__ scol)
{
    constexpr int BM = WGM * WM * 16, BN = WGN * WN * 16, BK = 64;
    const int z = blockIdx.z;
    A += (size_t)z * strideA;
    B += (size_t)z * strideB;
    if constexpr (MODE == 4 || MODE == 5) rsum += (size_t)z * 1024;
    if constexpr (MODE == 3 || MODE == 5) srow += (size_t)z * 1024;
    if constexpr (MODE == 5) scol += (size_t)z * 1024;
    const int m0 = blockIdx.x * BM, n0 = blockIdx.y * BN;
    __shared__ unsigned short lA[BM * BK];
    __shared__ unsigned short lB[BN * BK];
    const int tid = threadIdx.x, wave = tid >> 6, lane = tid & 63;
    const int wm = wave % WGM, wn = wave / WGM;
    const int fr = lane & 15, fq = lane >> 4;
    const int frx = fr & 7;
    const int lrow = lane >> 3;
    const int lcol = ((lane & 7) ^ lrow) * 8;   // XOR-swizzled global chunk
    f32x4 acc[WM][WN] = {};

    for (int k0 = 0; k0 < Kc; k0 += BK) {
        __syncthreads();
        #pragma unroll
        for (int cc = 0; cc < BM / 32; cc++) {
            int c = cc * 4 + wave;
            const unsigned short* src = A + (size_t)(m0 + c * 8 + lrow) * lda + k0 + lcol;
            gload_lds16(src, &lA[c * 512]);
        }
        #pragma unroll
        for (int cc = 0; cc < BN / 32; cc++) {
            int c = cc * 4 + wave;
            const unsigned short* src = B + (size_t)(n0 + c * 8 + lrow) * ldb + k0 + lcol;
            gload_lds16(src, &lB[c * 512]);
        }
        __syncthreads();
        #pragma unroll
        for (int kk = 0; kk < BK; kk += 32) {
            bf16x8 aF[WM], bF[WN];
            #pragma unroll
            for (int i = 0; i < WM; i++)
                aF[i] = *(const bf16x8*)&lA[(wm * WM * 16 + i * 16 + fr) * BK +
                                            ((((kk >> 3) + fq) ^ frx) << 3)];
            #pragma unroll
            for (int j = 0; j < WN; j++)
                bF[j] = *(const bf16x8*)&lB[(wn * WN * 16 + j * 16 + fr) * BK +
                                            ((((kk >> 3) + fq) ^ frx) << 3)];
            #pragma unroll
            for (int i = 0; i < WM; i++)
                #pragma unroll
                for (int j = 0; j < WN; j++)
                    acc[i][j] = __builtin_amdgcn_mfma_f32_16x16x32_bf16(aF[i], bF[j], acc[i][j], 0, 0, 0);
        }
    }

    #pragma unroll
    for (int i = 0; i < WM; i++) {
        const int row0 = m0 + wm * WM * 16 + i * 16 + fq * 4;
        float rs[4] = {0.0f, 0.0f, 0.0f, 0.0f};
        float irow[4];
        if constexpr (MODE == 3 || MODE == 5) {
            #pragma unroll
            for (int r = 0; r < 4; r++) irow[r] = 1.0f / srow[row0 + r];
        }
        #pragma unroll
        for (int j = 0; j < WN; j++) {
            const int col = n0 + wn * WN * 16 + j * 16 + fr;
            float icol = 0.0f;
            if constexpr (MODE == 5) icol = 1.0f / scol[col];
            #pragma unroll
            for (int r = 0; r < 4; r++) {
                const int row = row0 + r;
                float val = acc[i][j][r];
                if constexpr (MODE == 1) {
                    unsigned short* C = (unsigned short*)Cout;
                    float v = (val + bias[col]) * alpha;
                    int b = row >> 10, s = row & 1023;
                    int h = col >> 6,  d = col & 63;
                    C[(((size_t)b * NH + h) * SEQ + s) * DH + d] = f2b(v);
                } else if constexpr (MODE == 2) {
                    float* C = (float*)Cout;
                    C[(size_t)row * ldc + col] = val + bias[col];
                } else if constexpr (MODE == 3) {
                    unsigned short* C = (unsigned short*)Cout;
                    int zz = head0 + z;
                    int b = zz / NH, h = zz - b * NH;
                    C[((size_t)b * SEQ + row) * EMB + h * DH + col] = f2b(val * irow[r]);
                } else if constexpr (MODE == 4) {
                    unsigned short* C = (unsigned short*)Cout + (size_t)z * strideC;
                    float e = __expf(val);
                    C[(size_t)row * ldc + col] = f2b(e);
                    rs[r] += e;
                } else {  // MODE 5
                    unsigned short* C = (unsigned short*)Cout + (size_t)z * strideC;
                    float e = __expf(val * irow[r] * icol);
                    C[(size_t)row * ldc + col] = f2b(e);
                    rs[r] += e;
                }
            }
        }
        if constexpr (MODE == 4 || MODE == 5) {
            #pragma unroll
            for (int r = 0; r < 4; r++) {
                float v = rs[r];
                #pragma unroll
                for (int o = 1; o < 16; o <<= 1) v += __shfl_xor(v, o);
                if (fr == 0) atomicAdd(&rsum[row0 + r], v);
            }
        }
    }
}

// ---------- launcher ----------
extern "C" void kernel_launch(void* const* d_in, const int* in_sizes, int n_in,
                              void* d_out, int out_size, void* d_ws, size_t ws_size,
                              hipStream_t stream) {
    (void)in_sizes; (void)n_in; (void)out_size;
    const float* l    = (const float*)d_in[0];
    const float* sp   = (const float*)d_in[1];
    const float* p    = (const float*)d_in[2];
    const float* Wq   = (const float*)d_in[3];
    const float* bq   = (const float*)d_in[4];
    const float* Wksp = (const float*)d_in[5];
    const float* bksp = (const float*)d_in[6];
    const float* Wkp  = (const float*)d_in[7];
    const float* bkp  = (const float*)d_in[8];
    const float* Wvsp = (const float*)d_in[9];
    const float* bvsp = (const float*)d_in[10];
    const float* Wo   = (const float*)d_in[13];
    const float* bo   = (const float*)d_in[14];

    const size_t TOK  = (size_t)NB * SEQ * EMB;      // 6291456 elems
    const size_t WSZ  = (size_t)EMB * EMB;           // 589824 elems
    const size_t HB   = (size_t)SEQ * DH;            // 65536 elems per (b,h)
    const size_t MAT  = (size_t)SEQ * SEQ;           // 1048576 elems per (b,h)
    const int    ZALL = NB * NH;                     // 96

    char* wp = (char*)d_ws;
    auto alloc = [&](size_t bytes) {
        char* r = wp;
        wp += (bytes + 255) & ~(size_t)255;
        return r;
    };
    unsigned short* l_bf    = (unsigned short*)alloc(TOK * 2);
    unsigned short* sp_bf   = (unsigned short*)alloc(TOK * 2);
    unsigned short* p_bf    = (unsigned short*)alloc(TOK * 2);
    unsigned short* Wq_bf   = (unsigned short*)alloc(WSZ * 2);
    unsigned short* Wksp_bf = (unsigned short*)alloc(WSZ * 2);
    unsigned short* Wkp_bf  = (unsigned short*)alloc(WSZ * 2);
    unsigned short* Wvsp_bf = (unsigned short*)alloc(WSZ * 2);
    unsigned short* Wo_bf   = (unsigned short*)alloc(WSZ * 2);
    unsigned short* qb      = (unsigned short*)alloc(TOK * 2);  // [b,h,s,d]
    unsigned short* kspb    = (unsigned short*)alloc(TOK * 2);  // [b,h,k,d]
    unsigned short* kpb     = (unsigned short*)alloc(TOK * 2);  // [b,h,p,d]
    unsigned short* vb      = (unsigned short*)alloc(TOK * 2);  // [b,h,k,d]
    unsigned short* vTb     = (unsigned short*)alloc(TOK * 2);  // [b,h,d,k]
    unsigned short* attn    = (unsigned short*)alloc(TOK * 2);  // [b,p,e]
    float* sA = (float*)alloc((size_t)ZALL * SEQ * 4);          // sum_s exp(At)
    float* sB = (float*)alloc((size_t)ZALL * SEQ * 4);          // sum_s exp(Bt)
    float* sC = (float*)alloc((size_t)ZALL * SEQ * 4);          // sum_k exp(Cm)

    size_t used = (size_t)(wp - (char*)d_ws);
    size_t remain = (ws_size > used) ? (ws_size - used) : 0;
    const size_t perBatch = 3 * (size_t)NH * MAT * 2;           // At+Bt+C per batch
    int chunk = 8;
    while (chunk > 1 && (size_t)chunk * perBatch > remain) chunk >>= 1;
    unsigned short* At = (unsigned short*)alloc((size_t)chunk * NH * MAT * 2); // [z][k][s]
    unsigned short* Bt = (unsigned short*)alloc((size_t)chunk * NH * MAT * 2); // [z][p][s]
    unsigned short* Cm = (unsigned short*)alloc((size_t)chunk * NH * MAT * 2); // [z][p][k]

    const float scale = 0.125f;  // 64^-0.5

    // 0. zero the softmax-sum accumulators (poisoned 0xAA before every call)
    hipMemsetAsync(sA, 0, (size_t)3 * ZALL * SEQ * 4 + 512, stream);

    // 1. convert inputs & weights to bf16
    cvt_bf16<<<dim3(TOK / 4 / 256), 256, 0, stream>>>(l,  l_bf,  (int)(TOK / 4));
    cvt_bf16<<<dim3(TOK / 4 / 256), 256, 0, stream>>>(sp, sp_bf, (int)(TOK / 4));
    cvt_bf16<<<dim3(TOK / 4 / 256), 256, 0, stream>>>(p,  p_bf,  (int)(TOK / 4));
    cvt_bf16<<<dim3(WSZ / 4 / 256), 256, 0, stream>>>(Wq,   Wq_bf,   (int)(WSZ / 4));
    cvt_bf16<<<dim3(WSZ / 4 / 256), 256, 0, stream>>>(Wksp, Wksp_bf, (int)(WSZ / 4));
    cvt_bf16<<<dim3(WSZ / 4 / 256), 256, 0, stream>>>(Wkp,  Wkp_bf,  (int)(WSZ / 4));
    cvt_bf16<<<dim3(WSZ / 4 / 256), 256, 0, stream>>>(Wvsp, Wvsp_bf, (int)(WSZ / 4));
    cvt_bf16<<<dim3(WSZ / 4 / 256), 256, 0, stream>>>(Wo,   Wo_bf,   (int)(WSZ / 4));

    // 2. projections -> head-split bf16, scaled
    const dim3 gproj(64, 6, 1);
    gemm_nt<2,2,4,4,1><<<gproj, 256, 0, stream>>>(l_bf,  Wq_bf,   qb,   bq,   scale, EMB, EMB, EMB, 0, 0, 0, 0, 0, nullptr, nullptr, nullptr);
    gemm_nt<2,2,4,4,1><<<gproj, 256, 0, stream>>>(sp_bf, Wksp_bf, kspb, bksp, scale, EMB, EMB, EMB, 0, 0, 0, 0, 0, nullptr, nullptr, nullptr);
    gemm_nt<2,2,4,4,1><<<gproj, 256, 0, stream>>>(p_bf,  Wkp_bf,  kpb,  bkp,  scale, EMB, EMB, EMB, 0, 0, 0, 0, 0, nullptr, nullptr, nullptr);
    gemm_nt<2,2,4,4,1><<<gproj, 256, 0, stream>>>(sp_bf, Wvsp_bf, vb,   bvsp, scale, EMB, EMB, EMB, 0, 0, 0, 0, 0, nullptr, nullptr, nullptr);

    // 3. v transpose [z][k][d] -> [z][d][k]
    transpose_v<<<dim3(16, ZALL), 256, 0, stream>>>(vb, vTb);

    // 4. attention, chunked over batches
    for (int b0 = 0; b0 < NB; b0 += chunk) {
        const int ZH = chunk * NH;
        const int head0 = b0 * NH;
        const unsigned short* qz   = qb   + (size_t)head0 * HB;
        const unsigned short* kspz = kspb + (size_t)head0 * HB;
        const unsigned short* kpz  = kpb  + (size_t)head0 * HB;
        const unsigned short* vTz  = vTb  + (size_t)head0 * HB;
        float* sAz = sA + (size_t)head0 * SEQ;
        float* sBz = sB + (size_t)head0 * SEQ;
        float* sCz = sC + (size_t)head0 * SEQ;
        // exp-logits (transposed) + row sums:
        //   At[k,s] = exp(ksp[k]·q[s]), sA[k] = sum_s
        //   Bt[p,s] = exp(kp[p]·q[s]),  sB[p] = sum_s
        gemm_nt<2,2,4,4,4><<<dim3(8, 8, ZH), 256, 0, stream>>>(kspz, qz, At, nullptr, 1.0f,
            DH, DH, DH, SEQ, HB, HB, MAT, 0, sAz, nullptr, nullptr);
        gemm_nt<2,2,4,4,4><<<dim3(8, 8, ZH), 256, 0, stream>>>(kpz,  qz, Bt, nullptr, 1.0f,
            DH, DH, DH, SEQ, HB, HB, MAT, 0, sBz, nullptr, nullptr);
        // sp2p: Cm[p,k] = exp( (sum_s Bt At) / (sB[p] sA[k]) ), sC[p] = sum_k
        gemm_nt<2,2,4,4,5><<<dim3(8, 8, ZH), 256, 0, stream>>>(Bt, At, Cm, nullptr, 1.0f,
            SEQ, SEQ, SEQ, SEQ, MAT, MAT, MAT, 0, sCz, sBz, sAz);
        // pv: attn[b, p, h*64+d] = (1/sC[p]) sum_k Cm[p,k] vT[d,k]
        gemm_nt<4,1,2,4,3><<<dim3(8, 1, ZH), 256, 0, stream>>>(Cm, vTz, attn, nullptr, 1.0f,
            SEQ, SEQ, SEQ, 0, MAT, HB, 0, head0, nullptr, sCz, nullptr);
    }

    // 5. output projection -> fp32 d_out
    gemm_nt<2,2,4,4,2><<<gproj, 256, 0, stream>>>(attn, Wo_bf, d_out, bo, 1.0f,
        EMB, EMB, EMB, EMB, 0, 0, 0, 0, nullptr, nullptr, nullptr);
}

// Round 4
// 768.183 us; speedup vs baseline: 1.6680x; 1.3270x over previous
//
#include <hip/hip_runtime.h>
#include <stdint.h>

// ---------- constants ----------
static constexpr int SEQ = 1024;   // sen_len == sp_len == p_len
static constexpr int NH  = 12;
static constexpr int DH  = 64;
static constexpr int EMB = 768;
static constexpr int NB  = 8;

typedef __attribute__((ext_vector_type(8))) short bf16x8;
typedef __attribute__((ext_vector_type(4))) short s16x4;
typedef __attribute__((ext_vector_type(4))) float f32x4;

__device__ __forceinline__ float b2f(short s) {
    return __uint_as_float(((unsigned)(unsigned short)s) << 16);
}
__device__ __forceinline__ unsigned short f2b(float f) {
    unsigned u = __float_as_uint(f);
    unsigned rnd = 0x7fffu + ((u >> 16) & 1u);
    return (unsigned short)((u + rnd) >> 16);
}

__device__ __forceinline__ void gload_lds16(const void* g, void* l) {
    auto gp = reinterpret_cast<const __attribute__((address_space(1))) unsigned*>(
        reinterpret_cast<uintptr_t>(g));
    auto lp = reinterpret_cast<__attribute__((address_space(3))) unsigned*>(
        reinterpret_cast<uintptr_t>(l));
    __builtin_amdgcn_global_load_lds(gp, lp, 16, 0, 0);
}

// ---------- fp32 -> bf16 convert ----------
__global__ __launch_bounds__(256) void cvt_bf16(const float* __restrict__ in,
                                                unsigned short* __restrict__ out, int n4) {
    int i = blockIdx.x * 256 + threadIdx.x;
    if (i >= n4) return;
    float4 v = ((const float4*)in)[i];
    s16x4 o;
    o[0] = (short)f2b(v.x); o[1] = (short)f2b(v.y);
    o[2] = (short)f2b(v.z); o[3] = (short)f2b(v.w);
    ((s16x4*)out)[i] = o;
}

// ---------- transpose v [z][1024][64] -> vT [z][64][1024] ----------
__global__ __launch_bounds__(256) void transpose_v(const unsigned short* __restrict__ v,
                                                   unsigned short* __restrict__ vt) {
    const int zz = blockIdx.y;          // head-batch 0..95
    const int s0 = blockIdx.x * 64;     // 16 blocks of 64 s
    __shared__ unsigned short tile[64][80];
    const int t = threadIdx.x;
    {
        int rs = t >> 2;                // s within tile
        int cd = (t & 3) * 16;          // d start
        const unsigned short* src = v + ((size_t)zz * SEQ + s0 + rs) * DH + cd;
        *(bf16x8*)&tile[rs][cd]     = *(const bf16x8*)src;
        *(bf16x8*)&tile[rs][cd + 8] = *(const bf16x8*)(src + 8);
    }
    __syncthreads();
    {
        int rd = t >> 2;                // d row
        int cs = (t & 3) * 16;          // s chunk
        unsigned short o[16];
        #pragma unroll
        for (int j = 0; j < 16; j++) o[j] = tile[cs + j][rd];
        unsigned short* dst = vt + ((size_t)zz * DH + rd) * SEQ + s0 + cs;
        *(bf16x8*)dst       = *(const bf16x8*)&o[0];
        *(bf16x8*)(dst + 8) = *(const bf16x8*)&o[8];
    }
}

// ---------- templated NT GEMM: C[M,N] = A[M,K] @ B[N,K]^T variants ----------
// LDS XOR-swizzled (slot (r, chunk j) holds global chunk j^(r&7)) -> 0 bank
// conflicts with global_load_lds's pinned base+lane*16 destination.
//
// TMH>0 enables XCD-aware block swizzle: 1D grid, blk%8 = XCD (round-robin
// dispatch heuristic), contiguous work ids per XCD so one head's TMH*TNH
// tiles run on ONE XCD -> its 4MB L2 holds that head's operands (At+Bt =
// exactly 4MB for sp2p). R3 counters: sp2p FETCH was 111MB vs 48MB
// compulsory because heads were striped across all 8 XCD L2s.
//
// MODE 1: projection: (acc + bias[col]) * alpha -> bf16 head-split [b,h,s,d]
// MODE 2: fp32 row-major out + bias[col] (final output)
// MODE 3: pv: (val * 1/srow[row]) -> bf16 head-merge out [b, p, h*64+d]
// MODE 4: logits: e=exp(val) -> bf16 out; atomicAdd row sums into rsum[row]
// MODE 5: sp2p: e=exp(val/(srow[row]*scol[col])) -> bf16; atomicAdd rsum[row]
// Softmax normalizers factor out of the s-contraction, so MODE 4/5/3 together
// implement softmax_k( softmax_s(B)·softmax_s(A)^T )·V with zero extra passes.
// exp without max-subtraction is safe: logits |x| < ~0.3 by construction.
template<int WGM, int WGN, int WM, int WN, int MODE, int TMH, int TNH>
__global__ __launch_bounds__(256) void gemm_nt(
    const unsigned short* __restrict__ A, const unsigned short* __restrict__ B,
    void* __restrict__ Cout, const float* __restrict__ bias, float alpha,
    int Kc, int lda, int ldb, int ldc,
    size_t strideA, size_t strideB, size_t strideC, int head0,
    float* __restrict__ rsum, const float* __restrict__ srow,
    const float* __restrict__ scol)
{
    constexpr int BM = WGM * WM * 16, BN = WGN * WN * 16, BK = 64;
    int z, m0, n0;
    if constexpr (TMH > 0) {
        const int n   = blockIdx.x;
        const int per = gridDim.x >> 3;          // blocks per XCD
        const int w   = per * (n & 7) + (n >> 3);
        constexpr int BPH = TMH * TNH;           // blocks per head (pow2)
        z = w / BPH;
        const int t = w - z * BPH;
        m0 = (t % TMH) * BM;
        n0 = (t / TMH) * BN;
    } else {
        z = blockIdx.z; m0 = blockIdx.x * BM; n0 = blockIdx.y * BN;
    }
    A += (size_t)z * strideA;
    B += (size_t)z * strideB;
    if constexpr (MODE == 4 || MODE == 5) rsum += (size_t)z * 1024;
    if constexpr (MODE == 3 || MODE == 5) srow += (size_t)z * 1024;
    if constexpr (MODE == 5) scol += (size_t)z * 1024;
    __shared__ unsigned short lA[BM * BK];
    __shared__ unsigned short lB[BN * BK];
    const int tid = threadIdx.x, wave = tid >> 6, lane = tid & 63;
    const int wm = wave % WGM, wn = wave / WGM;
    const int fr = lane & 15, fq = lane >> 4;
    const int frx = fr & 7;
    const int lrow = lane >> 3;
    const int lcol = ((lane & 7) ^ lrow) * 8;   // XOR-swizzled global chunk
    f32x4 acc[WM][WN] = {};

    for (int k0 = 0; k0 < Kc; k0 += BK) {
        __syncthreads();
        #pragma unroll
        for (int cc = 0; cc < BM / 32; cc++) {
            int c = cc * 4 + wave;
            const unsigned short* src = A + (size_t)(m0 + c * 8 + lrow) * lda + k0 + lcol;
            gload_lds16(src, &lA[c * 512]);
        }
        #pragma unroll
        for (int cc = 0; cc < BN / 32; cc++) {
            int c = cc * 4 + wave;
            const unsigned short* src = B + (size_t)(n0 + c * 8 + lrow) * ldb + k0 + lcol;
            gload_lds16(src, &lB[c * 512]);
        }
        __syncthreads();
        #pragma unroll
        for (int kk = 0; kk < BK; kk += 32) {
            bf16x8 aF[WM], bF[WN];
            #pragma unroll
            for (int i = 0; i < WM; i++)
                aF[i] = *(const bf16x8*)&lA[(wm * WM * 16 + i * 16 + fr) * BK +
                                            ((((kk >> 3) + fq) ^ frx) << 3)];
            #pragma unroll
            for (int j = 0; j < WN; j++)
                bF[j] = *(const bf16x8*)&lB[(wn * WN * 16 + j * 16 + fr) * BK +
                                            ((((kk >> 3) + fq) ^ frx) << 3)];
            #pragma unroll
            for (int i = 0; i < WM; i++)
                #pragma unroll
                for (int j = 0; j < WN; j++)
                    acc[i][j] = __builtin_amdgcn_mfma_f32_16x16x32_bf16(aF[i], bF[j], acc[i][j], 0, 0, 0);
        }
    }

    #pragma unroll
    for (int i = 0; i < WM; i++) {
        const int row0 = m0 + wm * WM * 16 + i * 16 + fq * 4;
        float rs[4] = {0.0f, 0.0f, 0.0f, 0.0f};
        float irow[4];
        if constexpr (MODE == 3 || MODE == 5) {
            #pragma unroll
            for (int r = 0; r < 4; r++) irow[r] = 1.0f / srow[row0 + r];
        }
        #pragma unroll
        for (int j = 0; j < WN; j++) {
            const int col = n0 + wn * WN * 16 + j * 16 + fr;
            float icol = 0.0f;
            if constexpr (MODE == 5) icol = 1.0f / scol[col];
            #pragma unroll
            for (int r = 0; r < 4; r++) {
                const int row = row0 + r;
                float val = acc[i][j][r];
                if constexpr (MODE == 1) {
                    unsigned short* C = (unsigned short*)Cout;
                    float v = (val + bias[col]) * alpha;
                    int b = row >> 10, s = row & 1023;
                    int h = col >> 6,  d = col & 63;
                    C[(((size_t)b * NH + h) * SEQ + s) * DH + d] = f2b(v);
                } else if constexpr (MODE == 2) {
                    float* C = (float*)Cout;
                    C[(size_t)row * ldc + col] = val + bias[col];
                } else if constexpr (MODE == 3) {
                    unsigned short* C = (unsigned short*)Cout;
                    int zz = head0 + z;
                    int b = zz / NH, h = zz - b * NH;
                    C[((size_t)b * SEQ + row) * EMB + h * DH + col] = f2b(val * irow[r]);
                } else if constexpr (MODE == 4) {
                    unsigned short* C = (unsigned short*)Cout + (size_t)z * strideC;
                    float e = __expf(val);
                    C[(size_t)row * ldc + col] = f2b(e);
                    rs[r] += e;
                } else {  // MODE 5
                    unsigned short* C = (unsigned short*)Cout + (size_t)z * strideC;
                    float e = __expf(val * irow[r] * icol);
                    C[(size_t)row * ldc + col] = f2b(e);
                    rs[r] += e;
                }
            }
        }
        if constexpr (MODE == 4 || MODE == 5) {
            #pragma unroll
            for (int r = 0; r < 4; r++) {
                float v = rs[r];
                #pragma unroll
                for (int o = 1; o < 16; o <<= 1) v += __shfl_xor(v, o);
                if (fr == 0) atomicAdd(&rsum[row0 + r], v);
            }
        }
    }
}

// ---------- launcher ----------
extern "C" void kernel_launch(void* const* d_in, const int* in_sizes, int n_in,
                              void* d_out, int out_size, void* d_ws, size_t ws_size,
                              hipStream_t stream) {
    (void)in_sizes; (void)n_in; (void)out_size;
    const float* l    = (const float*)d_in[0];
    const float* sp   = (const float*)d_in[1];
    const float* p    = (const float*)d_in[2];
    const float* Wq   = (const float*)d_in[3];
    const float* bq   = (const float*)d_in[4];
    const float* Wksp = (const float*)d_in[5];
    const float* bksp = (const float*)d_in[6];
    const float* Wkp  = (const float*)d_in[7];
    const float* bkp  = (const float*)d_in[8];
    const float* Wvsp = (const float*)d_in[9];
    const float* bvsp = (const float*)d_in[10];
    const float* Wo   = (const float*)d_in[13];
    const float* bo   = (const float*)d_in[14];

    const size_t TOK  = (size_t)NB * SEQ * EMB;      // 6291456 elems
    const size_t WSZ  = (size_t)EMB * EMB;           // 589824 elems
    const size_t HB   = (size_t)SEQ * DH;            // 65536 elems per (b,h)
    const size_t MAT  = (size_t)SEQ * SEQ;           // 1048576 elems per (b,h)
    const int    ZALL = NB * NH;                     // 96

    char* wp = (char*)d_ws;
    auto alloc = [&](size_t bytes) {
        char* r = wp;
        wp += (bytes + 255) & ~(size_t)255;
        return r;
    };
    // ---- persistent region ----
    unsigned short* Wq_bf   = (unsigned short*)alloc(WSZ * 2);
    unsigned short* Wksp_bf = (unsigned short*)alloc(WSZ * 2);
    unsigned short* Wkp_bf  = (unsigned short*)alloc(WSZ * 2);
    unsigned short* Wvsp_bf = (unsigned short*)alloc(WSZ * 2);
    unsigned short* Wo_bf   = (unsigned short*)alloc(WSZ * 2);
    unsigned short* qb      = (unsigned short*)alloc(TOK * 2);  // [b,h,s,d]
    unsigned short* kspb    = (unsigned short*)alloc(TOK * 2);  // [b,h,k,d]
    unsigned short* kpb     = (unsigned short*)alloc(TOK * 2);  // [b,h,p,d]
    unsigned short* vTb     = (unsigned short*)alloc(TOK * 2);  // [b,h,d,k]
    unsigned short* attn    = (unsigned short*)alloc(TOK * 2);  // [b,p,e]
    float* sA = (float*)alloc((size_t)ZALL * SEQ * 4);          // sum_s exp(At)
    float* sB = (float*)alloc((size_t)ZALL * SEQ * 4);          // sum_s exp(Bt)
    float* sC = (float*)alloc((size_t)ZALL * SEQ * 4);          // sum_k exp(Cm)

    // ---- scratch region: stage-1 buffers overlap attention buffers ----
    // l_bf/sp_bf/p_bf dead after projections; vb dead after transpose_v.
    char* scratch = wp;
    size_t avail = (ws_size > (size_t)(scratch - (char*)d_ws))
                   ? ws_size - (size_t)(scratch - (char*)d_ws) : 0;
    unsigned short* l_bf  = (unsigned short*)(scratch);
    unsigned short* sp_bf = (unsigned short*)(scratch + TOK * 2);
    unsigned short* p_bf  = (unsigned short*)(scratch + TOK * 4);
    unsigned short* vb    = (unsigned short*)(scratch + TOK * 6);
    const size_t PB = (size_t)NH * MAT * 2;          // 25.2 MB per buffer per batch
    int chunk = 8;
    while (chunk > 1 && 3 * PB * (size_t)chunk > avail) chunk >>= 1;
    unsigned short* At = (unsigned short*)(scratch);                      // [z][k][s]
    unsigned short* Bt = (unsigned short*)(scratch + (size_t)chunk * PB); // [z][p][s]
    unsigned short* Cm = (unsigned short*)(scratch + (size_t)chunk * PB * 2); // [z][p][k]

    const float scale = 0.125f;  // 64^-0.5

    // 0. zero the softmax-sum accumulators (ws poisoned 0xAA before every call)
    hipMemsetAsync(sA, 0, (size_t)3 * ZALL * SEQ * 4, stream);

    // 1. convert inputs & weights to bf16
    cvt_bf16<<<dim3(TOK / 4 / 256), 256, 0, stream>>>(l,  l_bf,  (int)(TOK / 4));
    cvt_bf16<<<dim3(TOK / 4 / 256), 256, 0, stream>>>(sp, sp_bf, (int)(TOK / 4));
    cvt_bf16<<<dim3(TOK / 4 / 256), 256, 0, stream>>>(p,  p_bf,  (int)(TOK / 4));
    cvt_bf16<<<dim3(WSZ / 4 / 256), 256, 0, stream>>>(Wq,   Wq_bf,   (int)(WSZ / 4));
    cvt_bf16<<<dim3(WSZ / 4 / 256), 256, 0, stream>>>(Wksp, Wksp_bf, (int)(WSZ / 4));
    cvt_bf16<<<dim3(WSZ / 4 / 256), 256, 0, stream>>>(Wkp,  Wkp_bf,  (int)(WSZ / 4));
    cvt_bf16<<<dim3(WSZ / 4 / 256), 256, 0, stream>>>(Wvsp, Wvsp_bf, (int)(WSZ / 4));
    cvt_bf16<<<dim3(WSZ / 4 / 256), 256, 0, stream>>>(Wo,   Wo_bf,   (int)(WSZ / 4));

    // 2. projections -> head-split bf16, scaled
    const dim3 gproj(64, 6, 1);
    gemm_nt<2,2,4,4,1,0,0><<<gproj, 256, 0, stream>>>(l_bf,  Wq_bf,   qb,   bq,   scale, EMB, EMB, EMB, 0, 0, 0, 0, 0, nullptr, nullptr, nullptr);
    gemm_nt<2,2,4,4,1,0,0><<<gproj, 256, 0, stream>>>(sp_bf, Wksp_bf, kspb, bksp, scale, EMB, EMB, EMB, 0, 0, 0, 0, 0, nullptr, nullptr, nullptr);
    gemm_nt<2,2,4,4,1,0,0><<<gproj, 256, 0, stream>>>(p_bf,  Wkp_bf,  kpb,  bkp,  scale, EMB, EMB, EMB, 0, 0, 0, 0, 0, nullptr, nullptr, nullptr);
    gemm_nt<2,2,4,4,1,0,0><<<gproj, 256, 0, stream>>>(sp_bf, Wvsp_bf, vb,   bvsp, scale, EMB, EMB, EMB, 0, 0, 0, 0, 0, nullptr, nullptr, nullptr);

    // 3. v transpose [z][k][d] -> [z][d][k]
    transpose_v<<<dim3(16, ZALL), 256, 0, stream>>>(vb, vTb);

    // 4. attention, chunked over batches (XCD-swizzled 1D grids)
    for (int b0 = 0; b0 < NB; b0 += chunk) {
        const int ZH = chunk * NH;
        const int head0 = b0 * NH;
        const unsigned short* qz   = qb   + (size_t)head0 * HB;
        const unsigned short* kspz = kspb + (size_t)head0 * HB;
        const unsigned short* kpz  = kpb  + (size_t)head0 * HB;
        const unsigned short* vTz  = vTb  + (size_t)head0 * HB;
        float* sAz = sA + (size_t)head0 * SEQ;
        float* sBz = sB + (size_t)head0 * SEQ;
        float* sCz = sC + (size_t)head0 * SEQ;
        // exp-logits (transposed) + row sums:
        //   At[k,s] = exp(ksp[k]·q[s]), sA[k] = sum_s
        //   Bt[p,s] = exp(kp[p]·q[s]),  sB[p] = sum_s
        gemm_nt<2,2,4,4,4,8,8><<<dim3(ZH * 64), 256, 0, stream>>>(kspz, qz, At, nullptr, 1.0f,
            DH, DH, DH, SEQ, HB, HB, MAT, 0, sAz, nullptr, nullptr);
        gemm_nt<2,2,4,4,4,8,8><<<dim3(ZH * 64), 256, 0, stream>>>(kpz,  qz, Bt, nullptr, 1.0f,
            DH, DH, DH, SEQ, HB, HB, MAT, 0, sBz, nullptr, nullptr);
        // sp2p: Cm[p,k] = exp( (sum_s Bt At) / (sB[p] sA[k]) ), sC[p] = sum_k
        gemm_nt<2,2,4,4,5,8,8><<<dim3(ZH * 64), 256, 0, stream>>>(Bt, At, Cm, nullptr, 1.0f,
            SEQ, SEQ, SEQ, SEQ, MAT, MAT, MAT, 0, sCz, sBz, sAz);
        // pv: attn[b, p, h*64+d] = (1/sC[p]) sum_k Cm[p,k] vT[d,k]  (64x64 tiles)
        gemm_nt<2,2,2,2,3,16,1><<<dim3(ZH * 16), 256, 0, stream>>>(Cm, vTz, attn, nullptr, 1.0f,
            SEQ, SEQ, SEQ, 0, MAT, HB, 0, head0, nullptr, sCz, nullptr);
    }

    // 5. output projection -> fp32 d_out
    gemm_nt<2,2,4,4,2,0,0><<<gproj, 256, 0, stream>>>(attn, Wo_bf, d_out, bo, 1.0f,
        EMB, EMB, EMB, EMB, 0, 0, 0, 0, nullptr, nullptr, nullptr);
}